// Round 6
// baseline (213.096 us; speedup 1.0000x reference)
//
#include <hip/hip_runtime.h>
#include <hip/hip_bf16.h>
#include <stdint.h>

// Problem: B=128, S=512, I=128, Hd=512, G=3*Hd=1536, M=B*S=65536.
//
// ALGEBRAIC FUSION (r4, kept): gi = x @ (W_ih@W_emb)^T + (W_ih@b_emb + b_ih)
// -> precompute W_fused (1536x128) + b_fused (1536), one K=128 GEMM + gates.
//
// Round 6: two kernels only.
//  wprep    : fp32-VALU mini-GEMM W_fused = W_ih@W_emb (single bf16 rounding,
//             better than the old dual-rounded bf16 MFMA path) + b_fused.
//             Replaces prep + fuse_gemm; removes the 48 MB x-cvt round trip.
//  gru_main : reads x fp32 DIRECTLY from d_in (A-frags built in registers,
//             2 aligned float4 loads + cvt per frag), B (W_fused) streamed
//             over 16 h-chunks double-buffered in LDS (2x24 KB only), gate
//             math fused, direct dword stores (no LDS repack).
#define M_TOT   65536
#define I_DIM   128
#define HD      512
#define HOFF    33488896   // 128*511*512, element offset of h_last in d_out
#define HROW    261632     // 511*512, per-b row stride of H

typedef __bf16 bf16x8 __attribute__((ext_vector_type(8)));
typedef float f32x4 __attribute__((ext_vector_type(4)));

// async global->LDS, 16B per lane (lane-scatter base+lane*16, m104/m108).
__device__ __forceinline__ void async_load16(const void* g, void* l) {
  __builtin_amdgcn_global_load_lds(
      (const __attribute__((address_space(1))) void*)g,
      (__attribute__((address_space(3))) void*)l, 16, 0, 0);
}

// v_rcp_f32: rel err 2^-22 — far below the 1.4e-2 abs threshold.
__device__ __forceinline__ float fastrcp(float x) {
  return __builtin_amdgcn_rcpf(x);
}
__device__ __forceinline__ float sigf(float x) {
  return fastrcp(1.0f + __expf(-x));
}
__device__ __forceinline__ float tanhfast(float x) {
  return 1.0f - 2.0f * fastrcp(__expf(2.0f * x) + 1.0f);
}

// ---------------------------------------------------------------------------
// wprep: W_fused[g,i] = sum_h wi[g,h]*wemb[h,i]  (fp32 FMA, bf16 out)
//        b_fused[g]   = b_ih[g] + sum_h wi[g,h]*b_emb[h]
// Grid 384 blocks x 256 thr; block = 4 g-rows. wi rows staged to LDS (8 KB),
// read back as wave-uniform ds_read_b128 broadcasts; we columns are
// lane-coalesced 512 B global loads (we = 256 KB, L2-hot).
// ---------------------------------------------------------------------------
__global__ __launch_bounds__(256) void wprep(
    const float* __restrict__ wi,     // (1536,512)
    const float* __restrict__ we,     // (512,128)
    const float* __restrict__ b_emb,  // (512)
    const float* __restrict__ b_ih,   // (1536)
    __hip_bfloat16* __restrict__ wf,  // (1536,128) out
    float* __restrict__ bfu)          // (1536) out
{
  __shared__ float wis[4 * 512];      // 8 KB
  __shared__ float bes[512];          // 2 KB
  const int tid = threadIdx.x;
  const int g0  = blockIdx.x * 4;

  // stage 4 wi rows (512 float4) + b_emb
#pragma unroll
  for (int j = 0; j < 2; ++j)
    ((float4*)wis)[j * 256 + tid] =
        ((const float4*)(wi + (size_t)g0 * HD))[j * 256 + tid];
  if (tid < 128) ((float4*)bes)[tid] = ((const float4*)b_emb)[tid];
  __syncthreads();

  const int i   = tid & 127;          // output column
  const int seg = tid >> 7;           // 0,1 -> g pair
  float a0 = 0.0f, a1 = 0.0f;
#pragma unroll 4
  for (int h = 0; h < 512; h += 4) {
    const f32x4 w0 = *(const f32x4*)&wis[(seg * 2 + 0) * 512 + h];
    const f32x4 w1 = *(const f32x4*)&wis[(seg * 2 + 1) * 512 + h];
#pragma unroll
    for (int j = 0; j < 4; ++j) {
      const float wev = we[(size_t)(h + j) * I_DIM + i];
      a0 = fmaf(w0[j], wev, a0);
      a1 = fmaf(w1[j], wev, a1);
    }
  }
  wf[(size_t)(g0 + seg * 2 + 0) * I_DIM + i] = __float2bfloat16(a0);
  wf[(size_t)(g0 + seg * 2 + 1) * I_DIM + i] = __float2bfloat16(a1);

  // b_fused: first wave, 4 dot products (lanes strided over h)
  if (tid < 64) {
#pragma unroll
    for (int g = 0; g < 4; ++g) {
      float s = 0.0f;
#pragma unroll
      for (int h = 0; h < 8; ++h) s += wis[g * 512 + tid + h * 64] * bes[tid + h * 64];
#pragma unroll
      for (int off = 32; off; off >>= 1) s += __shfl_down(s, off);
      if (tid == 0) bfu[g0 + g] = s + b_ih[g0 + g];
    }
  }
}

// ---------------------------------------------------------------------------
// gru_main: gi[m, g*512+h] = sum_i x[m,i]*W_fused[g*512+h,i]; gate math.
// Grid = 512 blocks (128 M-rows each, ALL 512 h) = 2 blocks/CU.
// 4 waves x 32 M-rows. A: x fp32 loaded DIRECT to registers (16 float4/lane,
// 128-B-per-16-lane coalesced), converted to bf16 frags af[4ks][2mi] once.
// B: W_fused streamed over 16 h-chunks of 32 h x 3 gates (96 rows), two
// half-K [96][64] tiles per buffer, double-buffered (2x24 KB = all LDS).
// Per chunk: stage next (6 loads/wave) | 24 ds_read_b128 | 48 MFMA (setprio)
// | gate math | 16 direct dword stores/lane | __syncthreads.
// ---------------------------------------------------------------------------
__device__ __forceinline__ void stage_B32(const __hip_bfloat16* __restrict__ wf,
                                          int hc, char* Bbuf,
                                          int w, int lrow, int gc) {
  const int h0 = hc * 32;
#pragma unroll
  for (int j = 0; j < 6; ++j) {
    const int idx = w * 6 + j;          // 0..23
    const int kh = idx / 12;            // K-half
    const int cr = idx % 12;            // 8-row chunk within [96]
    const int r  = cr * 8 + lrow;       // 0..95
    const int g  = r >> 5;              // gate
    const int hh = r & 31;              // h within chunk
    async_load16(wf + (size_t)(g * HD + h0 + hh) * I_DIM + kh * 64 + gc,
                 (void*)&((__hip_bfloat16*)Bbuf)[kh * 6144 + cr * 512]);
  }
}

__global__ __launch_bounds__(256, 2) void gru_main(
    const float* __restrict__ x_f,            // (65536,128) fp32 (d_in)
    const __hip_bfloat16* __restrict__ wf,    // (1536,128) bf16
    const float* __restrict__ bfu,            // (1536) fp32  b_fused
    const float* __restrict__ b_hh,           // (1536) fp32
    float* __restrict__ out)                  // H ++ h_last fp32
{
  __shared__ __align__(16) char smem[49152];  // B dbuf 2 x 24 KB

  const int tid  = threadIdx.x;
  const int w    = tid >> 6;
  const int lane = tid & 63;
  const int m0 = blockIdx.x * 128;
  const int wm = w * 32;                      // wave M-offset
  const int lrow = lane >> 3;
  const int gc   = ((lane & 7) ^ lrow) * 8;   // swizzled global element offset
  const int l15 = lane & 15;
  const int q   = lane >> 4;
  const int sx  = l15 & 7;

  // issue B(0) staging first, build A-frags while the loads fly
  stage_B32(wf, 0, smem, w, lrow, gc);

  // A fragments direct from global fp32: af[ks][mi], frag = 8 contiguous k
  bf16x8 af[4][2];
#pragma unroll
  for (int mi = 0; mi < 2; ++mi) {
    const float* xp = x_f + (size_t)(m0 + wm + mi * 16 + l15) * I_DIM + q * 8;
#pragma unroll
    for (int ks = 0; ks < 4; ++ks) {
      const float4 c0 = *(const float4*)(xp + ks * 32);
      const float4 c1 = *(const float4*)(xp + ks * 32 + 4);
      bf16x8 v;
      v[0] = (__bf16)c0.x; v[1] = (__bf16)c0.y;
      v[2] = (__bf16)c0.z; v[3] = (__bf16)c0.w;
      v[4] = (__bf16)c1.x; v[5] = (__bf16)c1.y;
      v[6] = (__bf16)c1.z; v[7] = (__bf16)c1.w;
      af[ks][mi] = v;
    }
  }
  __syncthreads();   // drains vmcnt(0): B(0) resident

#pragma unroll 2
  for (int hc = 0; hc < 16; ++hc) {
    const __hip_bfloat16* Bs = (const __hip_bfloat16*)(smem + (hc & 1) * 24576);
    if (hc < 15)
      stage_B32(wf, hc + 1, smem + ((hc + 1) & 1) * 24576, w, lrow, gc);
    __builtin_amdgcn_sched_barrier(0);        // pin stage issue at chunk top

    f32x4 acc[3][2][2];
#pragma unroll
    for (int g = 0; g < 3; ++g)
#pragma unroll
      for (int mi = 0; mi < 2; ++mi)
#pragma unroll
        for (int ni = 0; ni < 2; ++ni) acc[g][mi][ni] = (f32x4)0.0f;

    __builtin_amdgcn_s_setprio(1);
#pragma unroll
    for (int g = 0; g < 3; ++g)
#pragma unroll
      for (int ks = 0; ks < 4; ++ks) {
        const int half = ks >> 1;
        const int s = (((ks & 1) * 4 + q) ^ sx) * 8;
#pragma unroll
        for (int ni = 0; ni < 2; ++ni) {
          const bf16x8 bv =
              *(const bf16x8*)&Bs[half * 6144 + (g * 32 + ni * 16 + l15) * 64 + s];
#pragma unroll
          for (int mi = 0; mi < 2; ++mi)
            acc[g][mi][ni] = __builtin_amdgcn_mfma_f32_16x16x32_bf16(
                af[ks][mi], bv, acc[g][mi][ni], 0, 0, 0);
        }
      }
    __builtin_amdgcn_s_setprio(0);

    // gate math + direct dword stores (C/D layout: col=ni*16+l15, row=q*4+r)
    const int h0 = hc * 32;
#pragma unroll
    for (int ni = 0; ni < 2; ++ni) {
      const int col = h0 + ni * 16 + l15;
      const float br = bfu[col] + b_hh[col];
      const float bz = bfu[HD + col] + b_hh[HD + col];
      const float bn = bfu[2 * HD + col];
      const float bhn = b_hh[2 * HD + col];
#pragma unroll
      for (int mi = 0; mi < 2; ++mi) {
        const int mbase = m0 + wm + mi * 16 + q * 4;
#pragma unroll
        for (int r = 0; r < 4; ++r) {
          const float rr = sigf(acc[0][mi][ni][r] + br);
          const float zz = sigf(acc[1][mi][ni][r] + bz);
          const float nn = tanhfast(acc[2][mi][ni][r] + bn + rr * bhn);
          const float hv = (1.0f - zz) * nn;
          const int m = mbase + r;
          const int b = m >> 9;               // m / 512
          const int s = m & 511;              // m % 512
          float* dst = (s < 511)
              ? out + (size_t)b * HROW + (size_t)s * HD + col
              : out + (size_t)HOFF + (size_t)b * HD + col;
          *dst = hv;
        }
      }
    }
    __syncthreads();   // staging drained (vmcnt0) + B reads done -> swap safe
  }
}

extern "C" void kernel_launch(void* const* d_in, const int* in_sizes, int n_in,
                              void* d_out, int out_size, void* d_ws, size_t ws_size,
                              hipStream_t stream) {
  const float* x_f     = (const float*)d_in[0];   // (128,512,128)
  const float* w_emb_f = (const float*)d_in[1];   // (512,128)
  const float* b_emb   = (const float*)d_in[2];   // (512)
  const float* w_ih_f  = (const float*)d_in[3];   // (1536,512)
  const float* b_ih    = (const float*)d_in[4];   // (1536)
  const float* b_hh    = (const float*)d_in[5];   // (1536)
  float* out = (float*)d_out;

  // ws layout (bytes):
  //   [0, 384Ki)        W_fused bf16 (1536*128*2)
  //   [393216, +6Ki)    b_fused f32  (1536*4)
  char* ws = (char*)d_ws;
  __hip_bfloat16* wf_bf = (__hip_bfloat16*)(ws);
  float*          b_fu  = (float*)(ws + 393216);

  wprep<<<384, 256, 0, stream>>>(w_ih_f, w_emb_f, b_emb, b_ih, wf_bf, b_fu);

  gru_main<<<M_TOT / 128, 256, 0, stream>>>(x_f, wf_bf, b_fu, b_hh, out);
}